// Round 12
// baseline (289.431 us; speedup 1.0000x reference)
//
#include <hip/hip_runtime.h>

// MLP_48687749268221: out[e] = W3 @ relu(W2 @ relu(W1 @ concat(drug[i0],dis[i1]) + b1) + b2) + b3
// E = 2e6, dims 256 -> 128 -> 64 -> 1. bf16 MFMA, f32 accumulate.
// Round 12: FULL-OCCUPANCY build. Same 64-edge tile + chunked linear LDS (round 11,
// conflicts -86%), but 512-thread blocks: 4 blocks x 8 waves = 2048 thr/CU = 32 waves/CU
// (was 13.4). Wave (wn,wm) = unit-quarter x edge-half; per-block LDS/W1/MFMA identical to
// round 11. VGPR held <= 64 (launch_bounds(512,8)) by deferring all post-L1 constants.

typedef __bf16 bf16x8 __attribute__((ext_vector_type(8)));
typedef unsigned short u16x8 __attribute__((ext_vector_type(8)));
typedef float f32x4 __attribute__((ext_vector_type(4)));

static __device__ __forceinline__ unsigned short f2b(float f) {
  // f32 -> bf16 RTNE (inputs finite)
  unsigned int u = __builtin_bit_cast(unsigned int, f);
  u += 0x7FFFu + ((u >> 16) & 1u);
  return (unsigned short)(u >> 16);
}

static __device__ __forceinline__ f32x4 mfma_bf16(u16x8 a, u16x8 b, f32x4 c) {
  return __builtin_amdgcn_mfma_f32_16x16x32_bf16(
      __builtin_bit_cast(bf16x8, a), __builtin_bit_cast(bf16x8, b), c, 0, 0, 0);
}

// ---------- prologue 1: f32 tables -> bf16 tables ----------
__global__ void cvt_tables(const float* __restrict__ a, const float* __restrict__ b,
                           unsigned short* __restrict__ oa, unsigned short* __restrict__ ob,
                           int na, int nb) {
  const int t = blockIdx.x * blockDim.x + threadIdx.x;
  const int ta = na >> 3;
  const float* src;
  unsigned short* dst;
  int i;
  if (t < ta) {
    src = a; dst = oa; i = t;
  } else {
    i = t - ta;
    if (i >= (nb >> 3)) return;
    src = b; dst = ob;
  }
  const float4 f0 = *(const float4*)(src + i * 8);
  const float4 f1 = *(const float4*)(src + i * 8 + 4);
  u16x8 v;
  v[0] = f2b(f0.x); v[1] = f2b(f0.y); v[2] = f2b(f0.z); v[3] = f2b(f0.w);
  v[4] = f2b(f1.x); v[5] = f2b(f1.y); v[6] = f2b(f1.z); v[7] = f2b(f1.w);
  *(u16x8*)(dst + i * 8) = v;
}

// ---------- prologue 2: weights -> bf16 in A-fragment order ----------
// Frag (16x16x32): lane l holds elem[dim][k], dim = 16*t + (l&15), k = 32*kt + 8*(l>>4) + j.
// W1 slot t = (ut*8 + kt)*64 + l  (ut 0..7, kt 0..7); W2: (nt2*4 + kt)*64 + l (nt2 0..3, kt 0..3).
__global__ void cvt_weights(const float* __restrict__ W1, const float* __restrict__ W2,
                            unsigned short* __restrict__ o1, unsigned short* __restrict__ o2) {
  const int t = blockIdx.x * blockDim.x + threadIdx.x;
  if (t < 4096) {
    const int l = t & 63, kt = (t >> 6) & 7, ut = t >> 9;
    const int n = 16 * ut + (l & 15), k0 = 32 * kt + 8 * (l >> 4);
    const float* src = W1 + n * 256 + k0;
    u16x8 v;
#pragma unroll
    for (int j = 0; j < 8; ++j) v[j] = f2b(src[j]);
    *(u16x8*)(o1 + t * 8) = v;
  } else if (t < 5120) {
    const int u = t - 4096;
    const int l = u & 63, kt = (u >> 6) & 3, nt = u >> 8;
    const int n = 16 * nt + (l & 15), k0 = 32 * kt + 8 * (l >> 4);
    const float* src = W2 + n * 128 + k0;
    u16x8 v;
#pragma unroll
    for (int j = 0; j < 8; ++j) v[j] = f2b(src[j]);
    *(u16x8*)(o2 + u * 8) = v;
  }
}

// ---------- main fused kernel ----------
// 512 threads = 8 waves; wave (wn = w&3, wm = w>>2): L1 units [32wn,+32) x edges [32wm,+32);
// L2 n2-units [16wn,+16) x edges [32wm,+32). Tile = 64 edges.
// LDS (exactly 32768 B -> 4 blocks/CU = 32 waves):
//   A: 32 chunks x [64 edges x 16 B] (chunk = 4kt+lq); H1: 16 chunks aliased @0 after L1;
//   partials [4][64] f32 @16384 (dead upper-A, disjoint from H1).
__global__ __launch_bounds__(512, 8) void mlp_fused(
    const unsigned short* __restrict__ drugB, const unsigned short* __restrict__ disB,
    const int* __restrict__ eidx, const unsigned short* __restrict__ w1frag,
    const unsigned short* __restrict__ w2frag, const float* __restrict__ b1,
    const float* __restrict__ b2, const float* __restrict__ W3,
    const float* __restrict__ b3, float* __restrict__ out, int E) {
  __shared__ __align__(16) unsigned char smem[32768];
  unsigned char* Abase = smem;
  float* partials = (float*)(smem + 16384);

  const int tid = threadIdx.x;
  const int w = tid >> 6;
  const int wn = w & 3;    // unit quarter
  const int wm = w >> 2;   // edge half
  const int l = tid & 63;
  const int l15 = l & 15;
  const int lq = l >> 4;
  const int e0 = blockIdx.x * 64;

  // ---- gather: wave w stages feature block [32w,+32) (64 B) of ALL 64 edges; 1 edge/lane ----
  // chunks [4w, 4w+4), each write = 64 lanes x 16 B contiguous 1 KB -> conflict-free
  {
    int e = e0 + l;
    if (e >= E) e = E - 1;
    const int idx = eidx[(w >> 2) * E + e];  // w<4: drug row, w>=4: dis row
    const unsigned short* src = ((w < 4) ? drugB : disB) + (long)idx * 128 + (w & 3) * 32;
    unsigned char* wbase = Abase + (4 * w) * 1024 + l * 16;
#pragma unroll
    for (int i = 0; i < 4; ++i) {
      const u16x8 v = *(const u16x8*)(src + i * 8);
      *(u16x8*)(wbase + i * 1024) = v;
    }
  }
  __syncthreads();

  // ---- layer 1: D1[unit][edge]; A = W1 frags (2-deep stream), B = edge frags from LDS ----
  f32x4 acc1[2][2];
#pragma unroll
  for (int uti = 0; uti < 2; ++uti)
#pragma unroll
    for (int nt = 0; nt < 2; ++nt) acc1[uti][nt] = (f32x4){0.f, 0.f, 0.f, 0.f};

  const int aoff = lq * 1024 + (32 * wm + l15) * 16;  // B-read: + kt*4096 + nt*256
  const unsigned short* w1p = w1frag + ((2 * wn) * 512 + l) * 8;
  u16x8 nf[2][2];  // [kt parity][uti]; kt+2 prefetch (round-6 proven pattern)
  nf[0][0] = *(const u16x8*)(w1p);
  nf[0][1] = *(const u16x8*)(w1p + 512 * 8);
  nf[1][0] = *(const u16x8*)(w1p + 64 * 8);
  nf[1][1] = *(const u16x8*)(w1p + (512 + 64) * 8);
#pragma unroll
  for (int kt = 0; kt < 8; ++kt) {
    const u16x8 c0 = nf[kt & 1][0], c1 = nf[kt & 1][1];
    if (kt < 6) {
      nf[kt & 1][0] = *(const u16x8*)(w1p + ((kt + 2) * 64) * 8);
      nf[kt & 1][1] = *(const u16x8*)(w1p + ((512 + (kt + 2) * 64)) * 8);
    }
#pragma unroll
    for (int nt = 0; nt < 2; ++nt) {
      const u16x8 b = *(const u16x8*)(Abase + kt * 4096 + nt * 256 + aoff);
      acc1[0][nt] = mfma_bf16(c0, b, acc1[0][nt]);
      acc1[1][nt] = mfma_bf16(c1, b, acc1[1][nt]);
    }
  }
  __syncthreads();  // all waves done reading A before H1 overwrites chunks 0..15

  // ---- post-L1 constants (deferred to keep L1 VGPR <= 64; L2-hot, TLP hides latency) ----
  const float4 b1v0 = *(const float4*)(b1 + 32 * wn + 4 * lq);
  const float4 b1v1 = *(const float4*)(b1 + 32 * wn + 16 + 4 * lq);
  u16x8 w2f[4];
#pragma unroll
  for (int kt = 0; kt < 4; ++kt)
    w2f[kt] = *(const u16x8*)(w2frag + ((wn * 4 + kt) * 64 + l) * 8);
  const float4 b2v = *(const float4*)(b2 + 16 * wn + 4 * lq);
  const float4 w3v = *(const float4*)(W3 + 16 * wn + 4 * lq);

  // ---- H1 epilogue: bias+relu, ushort4 -> chunked H1 (chunk = 4wn + 2uti + (lq>>1)) ----
  // lane holds D1[32wn + 16uti + 4lq + i][32wm + 16nt + l15]
  {
    unsigned char* hw = Abase + (4 * wn + (lq >> 1)) * 1024 + (lq & 1) * 8 +
                        (32 * wm + l15) * 16;
#pragma unroll
    for (int uti = 0; uti < 2; ++uti) {
      const float4 bv = uti ? b1v1 : b1v0;
#pragma unroll
      for (int nt = 0; nt < 2; ++nt) {
        float h0 = acc1[uti][nt][0] + bv.x; h0 = h0 > 0.f ? h0 : 0.f;
        float h1 = acc1[uti][nt][1] + bv.y; h1 = h1 > 0.f ? h1 : 0.f;
        float h2 = acc1[uti][nt][2] + bv.z; h2 = h2 > 0.f ? h2 : 0.f;
        float h3 = acc1[uti][nt][3] + bv.w; h3 = h3 > 0.f ? h3 : 0.f;
        ushort4 hv;
        hv.x = f2b(h0); hv.y = f2b(h1); hv.z = f2b(h2); hv.w = f2b(h3);
        *(ushort4*)(hw + uti * 2048 + nt * 256) = hv;
      }
    }
  }
  __syncthreads();

  // ---- layer 2: D2[n2][edge]; A = W2 frags, B = H1 frags (chunk = 4kt+lq) ----
  f32x4 acc2[2];
  acc2[0] = (f32x4){0.f, 0.f, 0.f, 0.f};
  acc2[1] = (f32x4){0.f, 0.f, 0.f, 0.f};
#pragma unroll
  for (int kt = 0; kt < 4; ++kt) {
#pragma unroll
    for (int nt = 0; nt < 2; ++nt) {
      const u16x8 b = *(const u16x8*)(Abase + kt * 4096 + nt * 256 + aoff);
      acc2[nt] = mfma_bf16(w2f[kt], b, acc2[nt]);
    }
  }

  // ---- layer 3: relu(.+b2) dot W3 (4 units/lane), reduce over lq with 2 shuffles ----
#pragma unroll
  for (int nt = 0; nt < 2; ++nt) {
    float h0 = acc2[nt][0] + b2v.x; h0 = h0 > 0.f ? h0 : 0.f;
    float h1 = acc2[nt][1] + b2v.y; h1 = h1 > 0.f ? h1 : 0.f;
    float h2 = acc2[nt][2] + b2v.z; h2 = h2 > 0.f ? h2 : 0.f;
    float h3 = acc2[nt][3] + b2v.w; h3 = h3 > 0.f ? h3 : 0.f;
    float s = h0 * w3v.x + h1 * w3v.y + h2 * w3v.z + h3 * w3v.w;
    s += __shfl_xor(s, 16, 64);
    s += __shfl_xor(s, 32, 64);
    if (l < 16) partials[wn * 64 + 32 * wm + 16 * nt + l15] = s;
  }
  __syncthreads();

  if (tid < 64) {
    const int e = e0 + tid;
    if (e < E) {
      out[e] = partials[tid] + partials[64 + tid] + partials[128 + tid] +
               partials[192 + tid] + b3[0];
    }
  }
}

extern "C" void kernel_launch(void* const* d_in, const int* in_sizes, int n_in,
                              void* d_out, int out_size, void* d_ws, size_t ws_size,
                              hipStream_t stream) {
  const float* drug = (const float*)d_in[0];
  const float* dis = (const float*)d_in[1];
  const int* eidx = (const int*)d_in[2];
  const float* W1 = (const float*)d_in[3];
  const float* b1 = (const float*)d_in[4];
  const float* W2 = (const float*)d_in[5];
  const float* b2 = (const float*)d_in[6];
  const float* W3 = (const float*)d_in[7];
  const float* b3 = (const float*)d_in[8];
  float* out = (float*)d_out;

  const int na = in_sizes[0];           // 10000*128
  const int nb = in_sizes[1];           // 5000*128
  const int E = in_sizes[2] / 2;        // 2e6

  unsigned short* ws = (unsigned short*)d_ws;
  unsigned short* drugB = ws;
  unsigned short* disB = ws + na;
  unsigned short* w1f = ws + na + nb;
  unsigned short* w2f = w1f + 128 * 256;
  // total ws use: (na+nb)*2 + 81920 bytes ~= 3.92 MB

  const int tct = (na + nb) >> 3;
  cvt_tables<<<(tct + 255) / 256, 256, 0, stream>>>(drug, dis, drugB, disB, na, nb);
  cvt_weights<<<20, 256, 0, stream>>>(W1, W2, w1f, w2f);

  const int grid = (E + 63) / 64;
  mlp_fused<<<grid, 512, 0, stream>>>(drugB, disB, eidx, w1f, w2f, b1, b2, W3, b3, out, E);
}

// Round 13
// 287.075 us; speedup vs baseline: 1.0082x; 1.0082x over previous
//
#include <hip/hip_runtime.h>

// MLP_48687749268221: out[e] = W3 @ relu(W2 @ relu(W1 @ concat(drug[i0],dis[i1]) + b1) + b2) + b3
// E = 2e6, dims 256 -> 128 -> 64 -> 1. bf16 MFMA, f32 accumulate.
// Round 13: L1 switched to mfma_f32_32x32x16_bf16, (2,2) wave split (2 unit-tiles x 32 edges)
// -> L1 LDS B-reads halve (128->64/block), MFMA cycles -20%. W1 stream 2 loads/step x 16
// steps, 4-deep prefetch. Gather/L2/L3 byte-identical to round 11 (224us, conflicts 4e6).

typedef __bf16 bf16x8 __attribute__((ext_vector_type(8)));
typedef unsigned short u16x8 __attribute__((ext_vector_type(8)));
typedef float f32x4 __attribute__((ext_vector_type(4)));
typedef float f32x16 __attribute__((ext_vector_type(16)));

static __device__ __forceinline__ unsigned short f2b(float f) {
  // f32 -> bf16 RTNE (inputs finite)
  unsigned int u = __builtin_bit_cast(unsigned int, f);
  u += 0x7FFFu + ((u >> 16) & 1u);
  return (unsigned short)(u >> 16);
}

static __device__ __forceinline__ f32x4 mfma16(u16x8 a, u16x8 b, f32x4 c) {
  return __builtin_amdgcn_mfma_f32_16x16x32_bf16(
      __builtin_bit_cast(bf16x8, a), __builtin_bit_cast(bf16x8, b), c, 0, 0, 0);
}
static __device__ __forceinline__ f32x16 mfma32(u16x8 a, u16x8 b, f32x16 c) {
  return __builtin_amdgcn_mfma_f32_32x32x16_bf16(
      __builtin_bit_cast(bf16x8, a), __builtin_bit_cast(bf16x8, b), c, 0, 0, 0);
}

// ---------- prologue 1: f32 tables -> bf16 tables ----------
__global__ void cvt_tables(const float* __restrict__ a, const float* __restrict__ b,
                           unsigned short* __restrict__ oa, unsigned short* __restrict__ ob,
                           int na, int nb) {
  const int t = blockIdx.x * blockDim.x + threadIdx.x;
  const int ta = na >> 3;
  const float* src;
  unsigned short* dst;
  int i;
  if (t < ta) {
    src = a; dst = oa; i = t;
  } else {
    i = t - ta;
    if (i >= (nb >> 3)) return;
    src = b; dst = ob;
  }
  const float4 f0 = *(const float4*)(src + i * 8);
  const float4 f1 = *(const float4*)(src + i * 8 + 4);
  u16x8 v;
  v[0] = f2b(f0.x); v[1] = f2b(f0.y); v[2] = f2b(f0.z); v[3] = f2b(f0.w);
  v[4] = f2b(f1.x); v[5] = f2b(f1.y); v[6] = f2b(f1.z); v[7] = f2b(f1.w);
  *(u16x8*)(dst + i * 8) = v;
}

// ---------- prologue 2: weights -> bf16 in fragment order ----------
// W1 (32x32x16 A-frag): lane l holds W1[32*ut + (l&31)][16*s + 8*(l>>5) + j], j=0..7.
//   slot t = (ut*16 + s)*64 + l, ut 0..3, s 0..15  (4096 slots x 16 B = 64 KB).
// W2 (16x16x32 A-frag): lane l holds W2[16*nt2 + (l&15)][32*kt + 8*(l>>4) + j].
//   slot u = (nt2*4 + kt)*64 + l, nt2 0..3, kt 0..3.
__global__ void cvt_weights(const float* __restrict__ W1, const float* __restrict__ W2,
                            unsigned short* __restrict__ o1, unsigned short* __restrict__ o2) {
  const int t = blockIdx.x * blockDim.x + threadIdx.x;
  if (t < 4096) {
    const int l = t & 63, s = (t >> 6) & 15, ut = t >> 10;
    const int n = 32 * ut + (l & 31), k0 = 16 * s + 8 * (l >> 5);
    const float* src = W1 + n * 256 + k0;
    u16x8 v;
#pragma unroll
    for (int j = 0; j < 8; ++j) v[j] = f2b(src[j]);
    *(u16x8*)(o1 + t * 8) = v;
  } else if (t < 5120) {
    const int u = t - 4096;
    const int l = u & 63, kt = (u >> 6) & 3, nt = u >> 8;
    const int n = 16 * nt + (l & 15), k0 = 32 * kt + 8 * (l >> 4);
    const float* src = W2 + n * 128 + k0;
    u16x8 v;
#pragma unroll
    for (int j = 0; j < 8; ++j) v[j] = f2b(src[j]);
    *(u16x8*)(o2 + u * 8) = v;
  }
}

// ---------- main fused kernel ----------
// 256 threads = 4 waves. Tile = 64 edges.
// Gather: wave w stages feature-quarter [64w,+64) of all 64 edges (R11, conflict-free).
// L1 (32x32x16): wave (wn2 = w>>1, wm = w&1): units [64wn2,+64) as 2 tiles, edges [32wm,+32).
// L2+L3 (16x16x32): wave wn owns n2-units [16wn,+16), all 64 edges (R11).
// LDS (33792 B -> 4 blocks/CU): A 32 chunks x [64 x 16 B] (chunk = f>>3); H1 16 chunks
// aliased @0 after L1; partials [4][64] f32 @32768.
__global__ __launch_bounds__(256, 4) void mlp_fused(
    const unsigned short* __restrict__ drugB, const unsigned short* __restrict__ disB,
    const int* __restrict__ eidx, const unsigned short* __restrict__ w1frag,
    const unsigned short* __restrict__ w2frag, const float* __restrict__ b1,
    const float* __restrict__ b2, const float* __restrict__ W3,
    const float* __restrict__ b3, float* __restrict__ out, int E) {
  __shared__ __align__(16) unsigned char smem[33792];
  unsigned char* Abase = smem;
  float* partials = (float*)(smem + 32768);

  const int tid = threadIdx.x;
  const int w = tid >> 6;
  const int wn = w;          // L2 unit-quarter (R11 role)
  const int wn2 = w >> 1;    // L1 unit-half
  const int wm = w & 1;      // L1 edge-half
  const int l = tid & 63;
  const int l15 = l & 15;
  const int lq = l >> 4;
  const int hi = l >> 5;     // 0..1
  const int e0 = blockIdx.x * 64;

  // ---- gather: wave w holds feature-quarter [64w,+64) of its lane's edge row ----
  {
    int e = e0 + l;
    if (e >= E) e = E - 1;
    const int idx = eidx[(w >> 1) * E + e];  // w<2: drug, w>=2: dis
    const unsigned short* src = ((w < 2) ? drugB : disB) + (long)idx * 128 + (w & 1) * 64;
    unsigned char* wbase = Abase + w * 8192 + l * 16;
#pragma unroll
    for (int c = 0; c < 8; ++c) {
      const u16x8 v = *(const u16x8*)(src + c * 8);
      *(u16x8*)(wbase + c * 1024) = v;
    }
  }

  // ---- hoisted constants (hidden under gather): W2 frags, b2, W3 ----
  u16x8 w2f[4];
#pragma unroll
  for (int kt = 0; kt < 4; ++kt)
    w2f[kt] = *(const u16x8*)(w2frag + ((wn * 4 + kt) * 64 + l) * 8);
  const float4 b2v = *(const float4*)(b2 + 16 * wn + 4 * lq);
  const float4 w3v = *(const float4*)(W3 + 16 * wn + 4 * lq);
  __syncthreads();

  // ---- layer 1 (32x32x16): D1[unit][edge]; A = W1 frags (4-deep stream), B from LDS ----
  f32x16 acc[2];
#pragma unroll
  for (int i = 0; i < 16; ++i) { acc[0][i] = 0.f; acc[1][i] = 0.f; }

  // B-frag: lane l -> edge 32wm + (l&31), features [16s + 8hi, +8)
  const int boff = hi * 1024 + (32 * wm + (l & 31)) * 16;  // + s*2048
  // W1 frag (ut = 2wn2 + uti, s) at ((ut*16 + s)*64 + l)*8 shorts
  const unsigned short* w1p = w1frag + ((2 * wn2) * 1024 + l) * 8;
  u16x8 nf[4][2];  // [s&3][uti]; 4-deep prefetch (8 loads in flight)
#pragma unroll
  for (int s = 0; s < 4; ++s) {
    nf[s][0] = *(const u16x8*)(w1p + (s * 64) * 8);
    nf[s][1] = *(const u16x8*)(w1p + (1024 + s * 64) * 8);
  }
#pragma unroll
  for (int s = 0; s < 16; ++s) {
    const u16x8 c0 = nf[s & 3][0], c1 = nf[s & 3][1];
    if (s < 12) {
      nf[s & 3][0] = *(const u16x8*)(w1p + ((s + 4) * 64) * 8);
      nf[s & 3][1] = *(const u16x8*)(w1p + ((1024 + (s + 4) * 64)) * 8);
    }
    const u16x8 b = *(const u16x8*)(Abase + s * 2048 + boff);
    acc[0] = mfma32(c0, b, acc[0]);
    acc[1] = mfma32(c1, b, acc[1]);
  }
  __syncthreads();  // all waves done reading A before H1 overwrites chunks 0..15

  // ---- H1 epilogue: bias+relu, ushort4 of 4 consecutive units -> chunked H1 ----
  // lane holds D1[32*(2wn2+uti) + (r&3) + 8*(r>>2) + 4hi][32wm + (l&31)], r = 4p+i.
  {
    const int ebyte = (32 * wm + (l & 31)) * 16;
#pragma unroll
    for (int uti = 0; uti < 2; ++uti) {
#pragma unroll
      for (int p = 0; p < 4; ++p) {
        const float4 bv = *(const float4*)(b1 + 32 * (2 * wn2 + uti) + 8 * p + 4 * hi);
        float h0 = acc[uti][4 * p + 0] + bv.x; h0 = h0 > 0.f ? h0 : 0.f;
        float h1 = acc[uti][4 * p + 1] + bv.y; h1 = h1 > 0.f ? h1 : 0.f;
        float h2 = acc[uti][4 * p + 2] + bv.z; h2 = h2 > 0.f ? h2 : 0.f;
        float h3 = acc[uti][4 * p + 3] + bv.w; h3 = h3 > 0.f ? h3 : 0.f;
        ushort4 hv;
        hv.x = f2b(h0); hv.y = f2b(h1); hv.z = f2b(h2); hv.w = f2b(h3);
        *(ushort4*)(Abase + (4 * (2 * wn2 + uti) + p) * 1024 + ebyte + 8 * hi) = hv;
      }
    }
  }
  __syncthreads();

  // ---- layer 2 (16x16x32): D2[n2][edge]; A = W2 frags, B = H1 frags (chunk = 4kt+lq) ----
  const int aoff = lq * 1024 + l15 * 16;
  f32x4 acc2[4];
#pragma unroll
  for (int nt = 0; nt < 4; ++nt) acc2[nt] = (f32x4){0.f, 0.f, 0.f, 0.f};
#pragma unroll
  for (int kt = 0; kt < 4; ++kt) {
#pragma unroll
    for (int nt = 0; nt < 4; ++nt) {
      const u16x8 b = *(const u16x8*)(Abase + kt * 4096 + nt * 256 + aoff);
      acc2[nt] = mfma16(w2f[kt], b, acc2[nt]);
    }
  }

  // ---- layer 3: relu(.+b2) dot W3 (4 units/lane), reduce over lq with 2 shuffles ----
#pragma unroll
  for (int nt = 0; nt < 4; ++nt) {
    float h0 = acc2[nt][0] + b2v.x; h0 = h0 > 0.f ? h0 : 0.f;
    float h1 = acc2[nt][1] + b2v.y; h1 = h1 > 0.f ? h1 : 0.f;
    float h2 = acc2[nt][2] + b2v.z; h2 = h2 > 0.f ? h2 : 0.f;
    float h3 = acc2[nt][3] + b2v.w; h3 = h3 > 0.f ? h3 : 0.f;
    float s = h0 * w3v.x + h1 * w3v.y + h2 * w3v.z + h3 * w3v.w;
    s += __shfl_xor(s, 16, 64);
    s += __shfl_xor(s, 32, 64);
    if (l < 16) partials[wn * 64 + 16 * nt + l15] = s;
  }
  __syncthreads();

  if (tid < 64) {
    const int e = e0 + tid;
    if (e < E) {
      out[e] = partials[tid] + partials[64 + tid] + partials[128 + tid] +
               partials[192 + tid] + b3[0];
    }
  }
}

extern "C" void kernel_launch(void* const* d_in, const int* in_sizes, int n_in,
                              void* d_out, int out_size, void* d_ws, size_t ws_size,
                              hipStream_t stream) {
  const float* drug = (const float*)d_in[0];
  const float* dis = (const float*)d_in[1];
  const int* eidx = (const int*)d_in[2];
  const float* W1 = (const float*)d_in[3];
  const float* b1 = (const float*)d_in[4];
  const float* W2 = (const float*)d_in[5];
  const float* b2 = (const float*)d_in[6];
  const float* W3 = (const float*)d_in[7];
  const float* b3 = (const float*)d_in[8];
  float* out = (float*)d_out;

  const int na = in_sizes[0];           // 10000*128
  const int nb = in_sizes[1];           // 5000*128
  const int E = in_sizes[2] / 2;        // 2e6

  unsigned short* ws = (unsigned short*)d_ws;
  unsigned short* drugB = ws;
  unsigned short* disB = ws + na;
  unsigned short* w1f = ws + na + nb;
  unsigned short* w2f = w1f + 128 * 256;
  // total ws use: (na+nb)*2 + 81920 bytes ~= 3.92 MB

  const int tct = (na + nb) >> 3;
  cvt_tables<<<(tct + 255) / 256, 256, 0, stream>>>(drug, dis, drugB, disB, na, nb);
  cvt_weights<<<20, 256, 0, stream>>>(W1, W2, w1f, w2f);

  const int grid = (E + 63) / 64;
  mlp_fused<<<grid, 256, 0, stream>>>(drugB, disB, eidx, w1f, w2f, b1, b2, W3, b3, out, E);
}

// Round 14
// 233.890 us; speedup vs baseline: 1.2375x; 1.2274x over previous
//
#include <hip/hip_runtime.h>

// MLP_48687749268221: out[e] = W3 @ relu(W2 @ relu(W1 @ concat(drug[i0],dis[i1]) + b1) + b2) + b3
// E = 2e6, dims 256 -> 128 -> 64 -> 1. bf16 MFMA, f32 accumulate.
// Round 14: R11 (best, 224us) with the gather switched to __builtin_amdgcn_global_load_lds
// (async HBM/L2 -> LDS DMA, width=16). The chunked layout's dest is wave-uniform base +
// lane*16 — exactly the hardware pattern. Loads issue before the W2/bias hoist and drain
// at the existing __syncthreads. Everything else byte-identical to R11.

typedef __bf16 bf16x8 __attribute__((ext_vector_type(8)));
typedef unsigned short u16x8 __attribute__((ext_vector_type(8)));
typedef float f32x4 __attribute__((ext_vector_type(4)));

static __device__ __forceinline__ unsigned short f2b(float f) {
  // f32 -> bf16 RTNE (inputs finite)
  unsigned int u = __builtin_bit_cast(unsigned int, f);
  u += 0x7FFFu + ((u >> 16) & 1u);
  return (unsigned short)(u >> 16);
}

static __device__ __forceinline__ f32x4 mfma_bf16(u16x8 a, u16x8 b, f32x4 c) {
  return __builtin_amdgcn_mfma_f32_16x16x32_bf16(
      __builtin_bit_cast(bf16x8, a), __builtin_bit_cast(bf16x8, b), c, 0, 0, 0);
}

// ---------- prologue 1: f32 tables -> bf16 tables ----------
__global__ void cvt_tables(const float* __restrict__ a, const float* __restrict__ b,
                           unsigned short* __restrict__ oa, unsigned short* __restrict__ ob,
                           int na, int nb) {
  const int t = blockIdx.x * blockDim.x + threadIdx.x;
  const int ta = na >> 3;
  const float* src;
  unsigned short* dst;
  int i;
  if (t < ta) {
    src = a; dst = oa; i = t;
  } else {
    i = t - ta;
    if (i >= (nb >> 3)) return;
    src = b; dst = ob;
  }
  const float4 f0 = *(const float4*)(src + i * 8);
  const float4 f1 = *(const float4*)(src + i * 8 + 4);
  u16x8 v;
  v[0] = f2b(f0.x); v[1] = f2b(f0.y); v[2] = f2b(f0.z); v[3] = f2b(f0.w);
  v[4] = f2b(f1.x); v[5] = f2b(f1.y); v[6] = f2b(f1.z); v[7] = f2b(f1.w);
  *(u16x8*)(dst + i * 8) = v;
}

// ---------- prologue 2: weights -> bf16 in A-fragment order ----------
// Frag (16x16x32): lane l holds elem[dim][k], dim = 16*t + (l&15), k = 32*kt + 8*(l>>4) + j.
// W1 slot t = (ut*8 + kt)*64 + l  (ut 0..7, kt 0..7); W2: (nt2*4 + kt)*64 + l (nt2 0..3, kt 0..3).
__global__ void cvt_weights(const float* __restrict__ W1, const float* __restrict__ W2,
                            unsigned short* __restrict__ o1, unsigned short* __restrict__ o2) {
  const int t = blockIdx.x * blockDim.x + threadIdx.x;
  if (t < 4096) {
    const int l = t & 63, kt = (t >> 6) & 7, ut = t >> 9;
    const int n = 16 * ut + (l & 15), k0 = 32 * kt + 8 * (l >> 4);
    const float* src = W1 + n * 256 + k0;
    u16x8 v;
#pragma unroll
    for (int j = 0; j < 8; ++j) v[j] = f2b(src[j]);
    *(u16x8*)(o1 + t * 8) = v;
  } else if (t < 5120) {
    const int u = t - 4096;
    const int l = u & 63, kt = (u >> 6) & 3, nt = u >> 8;
    const int n = 16 * nt + (l & 15), k0 = 32 * kt + 8 * (l >> 4);
    const float* src = W2 + n * 128 + k0;
    u16x8 v;
#pragma unroll
    for (int j = 0; j < 8; ++j) v[j] = f2b(src[j]);
    *(u16x8*)(o2 + u * 8) = v;
  }
}

// ---------- main fused kernel ----------
// 256 threads = 4 waves; wave wn owns W1 units [32wn,+32) and W2 units [16wn,+16),
// sweeps all 64 edges (round-6/11 schedule). LDS (33792 B -> 4 blocks/CU):
//   A: 32 chunks x [64 edges x 16 B] @0 (chunk = kt*4+lq); H1: 16 chunks aliased @0
//   after L1 barrier; partials [4][64] f32 @32768.
__global__ __launch_bounds__(256, 4) void mlp_fused(
    const unsigned short* __restrict__ drugB, const unsigned short* __restrict__ disB,
    const int* __restrict__ eidx, const unsigned short* __restrict__ w1frag,
    const unsigned short* __restrict__ w2frag, const float* __restrict__ b1,
    const float* __restrict__ b2, const float* __restrict__ W3,
    const float* __restrict__ b3, float* __restrict__ out, int E) {
  __shared__ __align__(16) unsigned char smem[33792];
  unsigned char* Abase = smem;
  float* partials = (float*)(smem + 32768);

  const int tid = threadIdx.x;
  const int wn = tid >> 6;   // wave 0..3: unit-column quarter (and gather feature-quarter)
  const int l = tid & 63;
  const int l15 = l & 15;
  const int lq = l >> 4;
  const int e0 = blockIdx.x * 64;

  // per-lane invariant LDS offsets (all linear, no swizzle)
  const int aoff = lq * 1024 + l15 * 16;  // B-frag read: + kt*4096 + nt*256

  // ---- gather via global_load_lds: wave wn stages feature-quarter [64wn,+64) of its
  // lane's edge row; chunk (8wn+c) dest = uniform base + l*16 (HW-native), src per-lane ----
  {
    int e = e0 + l;
    if (e >= E) e = E - 1;
    const int idx = eidx[(wn >> 1) * E + e];  // wn<2: drug, wn>=2: dis
    const unsigned short* src = ((wn < 2) ? drugB : disB) + (long)idx * 128 + (wn & 1) * 64;
    unsigned char* wbase = Abase + wn * 8192 + l * 16;
#pragma unroll
    for (int c = 0; c < 8; ++c) {
      __builtin_amdgcn_global_load_lds(
          (const __attribute__((address_space(1))) unsigned int*)(src + c * 8),
          (__attribute__((address_space(3))) unsigned int*)(wbase + c * 1024),
          16, 0, 0);
    }
  }

  // ---- W2 A-frags resident (issued while gather DMAs are in flight), bias/W3 ----
  u16x8 w2f[4];
#pragma unroll
  for (int kt = 0; kt < 4; ++kt)
    w2f[kt] = *(const u16x8*)(w2frag + ((wn * 4 + kt) * 64 + l) * 8);
  const float4 b1v0 = *(const float4*)(b1 + 32 * wn + 4 * lq);
  const float4 b1v1 = *(const float4*)(b1 + 32 * wn + 16 + 4 * lq);
  const float4 b2v = *(const float4*)(b2 + 16 * wn + 4 * lq);
  const float4 w3v = *(const float4*)(W3 + 16 * wn + 4 * lq);
  __syncthreads();  // drains vmcnt(0): gather DMAs + hoist loads complete

  // ---- layer 1: D1[unit][edge]; A = W1 frags (2-deep stream), B = edge frags from LDS ----
  f32x4 acc1[2][4];
#pragma unroll
  for (int uti = 0; uti < 2; ++uti)
#pragma unroll
    for (int nt = 0; nt < 4; ++nt) acc1[uti][nt] = (f32x4){0.f, 0.f, 0.f, 0.f};

  const unsigned short* w1p = w1frag + ((2 * wn) * 512 + l) * 8;
  u16x8 nf[2][2];  // [kt parity][uti]; kt+2 prefetch (proven R6/R11 pattern)
  nf[0][0] = *(const u16x8*)(w1p);
  nf[0][1] = *(const u16x8*)(w1p + 512 * 8);
  nf[1][0] = *(const u16x8*)(w1p + 64 * 8);
  nf[1][1] = *(const u16x8*)(w1p + (512 + 64) * 8);
#pragma unroll
  for (int kt = 0; kt < 8; ++kt) {
    const u16x8 c0 = nf[kt & 1][0], c1 = nf[kt & 1][1];
    if (kt < 6) {
      nf[kt & 1][0] = *(const u16x8*)(w1p + ((kt + 2) * 64) * 8);
      nf[kt & 1][1] = *(const u16x8*)(w1p + ((512 + (kt + 2) * 64)) * 8);
    }
#pragma unroll
    for (int nt = 0; nt < 4; ++nt) {
      const u16x8 b = *(const u16x8*)(Abase + kt * 4096 + nt * 256 + aoff);
      acc1[0][nt] = mfma_bf16(c0, b, acc1[0][nt]);
      acc1[1][nt] = mfma_bf16(c1, b, acc1[1][nt]);
    }
  }
  __syncthreads();  // all waves done reading A before H1 overwrites chunks 0..15

  // ---- H1 epilogue: bias+relu, pack 4 bf16 -> 8B write, chunked layout ----
  // lane holds D1[u0..u0+4)[e], u0 = 32wn+16uti+4lq, e = 16nt+l15.
  {
    unsigned char* hw = Abase + wn * 4096 + (lq >> 1) * 1024 + (lq & 1) * 8 + l15 * 16;
#pragma unroll
    for (int uti = 0; uti < 2; ++uti) {
      const float4 bv = uti ? b1v1 : b1v0;
#pragma unroll
      for (int nt = 0; nt < 4; ++nt) {
        float h0 = acc1[uti][nt][0] + bv.x; h0 = h0 > 0.f ? h0 : 0.f;
        float h1 = acc1[uti][nt][1] + bv.y; h1 = h1 > 0.f ? h1 : 0.f;
        float h2 = acc1[uti][nt][2] + bv.z; h2 = h2 > 0.f ? h2 : 0.f;
        float h3 = acc1[uti][nt][3] + bv.w; h3 = h3 > 0.f ? h3 : 0.f;
        ushort4 hv;
        hv.x = f2b(h0); hv.y = f2b(h1); hv.z = f2b(h2); hv.w = f2b(h3);
        *(ushort4*)(hw + uti * 2048 + nt * 256) = hv;
      }
    }
  }
  __syncthreads();

  // ---- layer 2: D2[n2][edge]; A = W2 frags (resident), B = H1 frags from LDS ----
  f32x4 acc2[4];
#pragma unroll
  for (int nt = 0; nt < 4; ++nt) acc2[nt] = (f32x4){0.f, 0.f, 0.f, 0.f};
#pragma unroll
  for (int kt = 0; kt < 4; ++kt) {
#pragma unroll
    for (int nt = 0; nt < 4; ++nt) {
      const u16x8 b = *(const u16x8*)(Abase + kt * 4096 + nt * 256 + aoff);
      acc2[nt] = mfma_bf16(w2f[kt], b, acc2[nt]);
    }
  }

  // ---- layer 3: relu(.+b2) dot W3 (4 units per lane), reduce over lq with 2 shuffles ----
#pragma unroll
  for (int nt = 0; nt < 4; ++nt) {
    float h0 = acc2[nt][0] + b2v.x; h0 = h0 > 0.f ? h0 : 0.f;
    float h1 = acc2[nt][1] + b2v.y; h1 = h1 > 0.f ? h1 : 0.f;
    float h2 = acc2[nt][2] + b2v.z; h2 = h2 > 0.f ? h2 : 0.f;
    float h3 = acc2[nt][3] + b2v.w; h3 = h3 > 0.f ? h3 : 0.f;
    float s = h0 * w3v.x + h1 * w3v.y + h2 * w3v.z + h3 * w3v.w;
    s += __shfl_xor(s, 16, 64);
    s += __shfl_xor(s, 32, 64);
    if (l < 16) partials[wn * 64 + 16 * nt + l15] = s;
  }
  __syncthreads();

  if (tid < 64) {
    const int e = e0 + tid;
    if (e < E) {
      out[e] = partials[tid] + partials[64 + tid] + partials[128 + tid] +
               partials[192 + tid] + b3[0];
    }
  }
}

extern "C" void kernel_launch(void* const* d_in, const int* in_sizes, int n_in,
                              void* d_out, int out_size, void* d_ws, size_t ws_size,
                              hipStream_t stream) {
  const float* drug = (const float*)d_in[0];
  const float* dis = (const float*)d_in[1];
  const int* eidx = (const int*)d_in[2];
  const float* W1 = (const float*)d_in[3];
  const float* b1 = (const float*)d_in[4];
  const float* W2 = (const float*)d_in[5];
  const float* b2 = (const float*)d_in[6];
  const float* W3 = (const float*)d_in[7];
  const float* b3 = (const float*)d_in[8];
  float* out = (float*)d_out;

  const int na = in_sizes[0];           // 10000*128
  const int nb = in_sizes[1];           // 5000*128
  const int E = in_sizes[2] / 2;        // 2e6

  unsigned short* ws = (unsigned short*)d_ws;
  unsigned short* drugB = ws;
  unsigned short* disB = ws + na;
  unsigned short* w1f = ws + na + nb;
  unsigned short* w2f = w1f + 128 * 256;
  // total ws use: (na+nb)*2 + 81920 bytes ~= 3.92 MB

  const int tct = (na + nb) >> 3;
  cvt_tables<<<(tct + 255) / 256, 256, 0, stream>>>(drug, dis, drugB, disB, na, nb);
  cvt_weights<<<20, 256, 0, stream>>>(W1, W2, w1f, w2f);

  const int grid = (E + 63) / 64;
  mlp_fused<<<grid, 256, 0, stream>>>(drugB, disB, eidx, w1f, w2f, b1, b2, W3, b3, out, E);
}